// Round 1
// baseline (2753.946 us; speedup 1.0000x reference)
//
#include <hip/hip_runtime.h>

#define NT 256
#define RPB 32
#define NSTEP 32
#define DD 128

__device__ __forceinline__ float red32(float v) {
  v += __shfl_xor(v, 1);
  v += __shfl_xor(v, 2);
  v += __shfl_xor(v, 4);
  v += __shfl_xor(v, 8);
  v += __shfl_xor(v, 16);
  return v;
}

__device__ __forceinline__ float sigm_f(float x) { return 1.f / (1.f + __expf(-x)); }
__device__ __forceinline__ float tanh_f(float x) {
  x = fminf(15.f, fmaxf(-15.f, x));
  const float e = __expf(2.f * x);
  return (e - 1.f) / (e + 1.f);
}

// Stage one 32-output-row weight tile into padded LDS, then each thread
// accumulates 4 row-dots (rows rg, rg+8, rg+16, rg+24) for its output g=gl.
#define GEMM_TILE(WBASE, INLDS, A0, A1, A2, A3)                                   \
  do {                                                                            \
    __syncthreads();                                                              \
    _Pragma("unroll")                                                             \
    for (int j = 0; j < 4; ++j) {                                                 \
      const int f = tid + NT * j;                                                 \
      const float4 v = reinterpret_cast<const float4*>(WBASE)[f];                 \
      const int e = f << 2;                                                       \
      *reinterpret_cast<float4*>(&Wt[0][0] + (e >> 7) * 132 + (e & 127)) = v;     \
    }                                                                             \
    __syncthreads();                                                              \
    {                                                                             \
      float t0 = 0.f, t1 = 0.f, t2 = 0.f, t3 = 0.f;                               \
      const float* wrow = &Wt[gl][0];                                             \
      _Pragma("unroll 2")                                                         \
      for (int d = 0; d < DD; d += 4) {                                           \
        const float4 wv = *reinterpret_cast<const float4*>(wrow + d);             \
        const float4 x0 = *reinterpret_cast<const float4*>(&INLDS[rg][d]);        \
        const float4 x1 = *reinterpret_cast<const float4*>(&INLDS[rg + 8][d]);    \
        const float4 x2 = *reinterpret_cast<const float4*>(&INLDS[rg + 16][d]);   \
        const float4 x3 = *reinterpret_cast<const float4*>(&INLDS[rg + 24][d]);   \
        t0 += wv.x * x0.x; t0 += wv.y * x0.y; t0 += wv.z * x0.z; t0 += wv.w * x0.w; \
        t1 += wv.x * x1.x; t1 += wv.y * x1.y; t1 += wv.z * x1.z; t1 += wv.w * x1.w; \
        t2 += wv.x * x2.x; t2 += wv.y * x2.y; t2 += wv.z * x2.z; t2 += wv.w * x2.w; \
        t3 += wv.x * x3.x; t3 += wv.y * x3.y; t3 += wv.z * x3.z; t3 += wv.w * x3.w; \
      }                                                                           \
      A0 = t0; A1 = t1; A2 = t2; A3 = t3;                                         \
    }                                                                             \
  } while (0)

__global__ __launch_bounds__(NT) void rec_kernel(
    const int* __restrict__ paths, const int* __restrict__ pmask,
    const float* __restrict__ emb,
    const float* __restrict__ Wi, const float* __restrict__ bi,
    const float* __restrict__ Wh, const float* __restrict__ bh,
    const float* __restrict__ Ww, const float* __restrict__ bw,
    const float* __restrict__ Wu, const float* __restrict__ bu,
    float* __restrict__ out)
{
  __shared__ float X[RPB][DD];    // 16 KB  current x_t for the block's 32 rows
  __shared__ float Hs[RPB][DD];   // 16 KB  hidden state
  __shared__ float Wt[32][132];   // 16.9 KB weight tile, +4-float pad: b128 reads conflict-free

  const int tid = threadIdx.x;
  const int r0 = blockIdx.x * RPB;
  const int gl = tid & 31;   // output index within a 32-g tile
  const int rg = tid >> 5;   // row group 0..7  (rows rg+8k)

  for (int i = tid; i < RPB * DD; i += NT) (&Hs[0][0])[i] = 0.f;

  const int lens[4] = { pmask[r0 + rg],      pmask[r0 + rg + 8],
                        pmask[r0 + rg + 16], pmask[r0 + rg + 24] };

  float bi_r[8], bh_r[8], bw_r[4], bu_r[4];
  #pragma unroll
  for (int w = 0; w < 8; ++w) { bi_r[w] = bi[gl + 32 * w]; bh_r[w] = bh[gl + 32 * w]; }
  #pragma unroll
  for (int w = 0; w < 4; ++w) { bw_r[w] = bw[gl + 32 * w]; bu_r[w] = bu[gl + 32 * w]; }

  __syncthreads();

  #pragma unroll 1
  for (int t = 0; t < NSTEP; ++t) {
    { // gather x_t = emb[paths[:, t]]  (first GEMM_TILE barrier orders these writes)
      const int row = tid >> 3;
      const int seg = tid & 7;
      const int p = paths[(r0 + row) * NSTEP + t];
      const float4* src = reinterpret_cast<const float4*>(emb + p * DD) + seg * 4;
      float4* dst = reinterpret_cast<float4*>(&X[row][0]) + seg * 4;
      const float4 a = src[0], b = src[1], c = src[2], d = src[3];
      dst[0] = a; dst[1] = b; dst[2] = c; dst[3] = d;
    }

    // ---- xi_pre = x @ Wi^T (G=256) ----
    float gz[4][8];
    #pragma unroll
    for (int tw = 0; tw < 8; ++tw)
      GEMM_TILE(Wi + tw * 32 * DD, X, gz[0][tw], gz[1][tw], gz[2][tw], gz[3][tw]);

    // ---- h2h_pre = h @ Wh^T (G=256) ----
    float hv[4][8];
    #pragma unroll
    for (int tw = 0; tw < 8; ++tw)
      GEMM_TILE(Wh + tw * 32 * DD, Hs, hv[0][tw], hv[1][tw], hv[2][tw], hv[3][tw]);

    // LN both (over 256), then gates = sigmoid(xi + h2h); gz := gates (z: tw<4, r: tw>=4)
    #pragma unroll
    for (int k = 0; k < 4; ++k) {
      float s = 0.f, q = 0.f;
      #pragma unroll
      for (int tw = 0; tw < 8; ++tw) {
        const float p = gz[k][tw] + bi_r[tw];
        gz[k][tw] = p; s += p; q += p * p;
      }
      s = red32(s); q = red32(q);
      const float mean = s * (1.f / 256.f);
      const float rstd = rsqrtf(fmaxf(q * (1.f / 256.f) - mean * mean, 0.f) + 1e-5f);
      float s2 = 0.f, q2 = 0.f;
      #pragma unroll
      for (int tw = 0; tw < 8; ++tw) {
        const float p = hv[k][tw] + bh_r[tw];
        hv[k][tw] = p; s2 += p; q2 += p * p;
      }
      s2 = red32(s2); q2 = red32(q2);
      const float mean2 = s2 * (1.f / 256.f);
      const float rstd2 = rsqrtf(fmaxf(q2 * (1.f / 256.f) - mean2 * mean2, 0.f) + 1e-5f);
      #pragma unroll
      for (int tw = 0; tw < 8; ++tw) {
        const float xin = (gz[k][tw] - mean) * rstd;
        const float hin = (hv[k][tw] - mean2) * rstd2;
        gz[k][tw] = sigm_f(xin + hin);
      }
    }

    // ---- xw_pre = x @ Ww^T, hu_pre = h @ Wu^T (G=128) ----
    float pw[4][4];
    #pragma unroll
    for (int tw = 0; tw < 4; ++tw)
      GEMM_TILE(Ww + tw * 32 * DD, X, pw[0][tw], pw[1][tw], pw[2][tw], pw[3][tw]);
    float pu[4][4];
    #pragma unroll
    for (int tw = 0; tw < 4; ++tw)
      GEMM_TILE(Wu + tw * 32 * DD, Hs, pu[0][tw], pu[1][tw], pu[2][tw], pu[3][tw]);

    float hn[4][4];
    #pragma unroll
    for (int k = 0; k < 4; ++k) {
      float s = 0.f, q = 0.f;
      #pragma unroll
      for (int tw = 0; tw < 4; ++tw) {
        const float p = pw[k][tw] + bw_r[tw];
        pw[k][tw] = p; s += p; q += p * p;
      }
      s = red32(s); q = red32(q);
      const float mean = s * (1.f / 128.f);
      const float rstd = rsqrtf(fmaxf(q * (1.f / 128.f) - mean * mean, 0.f) + 1e-5f);
      float s2 = 0.f, q2 = 0.f;
      #pragma unroll
      for (int tw = 0; tw < 4; ++tw) {
        const float p = pu[k][tw] + bu_r[tw];
        pu[k][tw] = p; s2 += p; q2 += p * p;
      }
      s2 = red32(s2); q2 = red32(q2);
      const float mean2 = s2 * (1.f / 128.f);
      const float rstd2 = rsqrtf(fmaxf(q2 * (1.f / 128.f) - mean2 * mean2, 0.f) + 1e-5f);
      #pragma unroll
      for (int tw = 0; tw < 4; ++tw) {
        const float xwn = (pw[k][tw] - mean) * rstd;
        const float hun = (pu[k][tw] - mean2) * rstd2;
        const float z = gz[k][tw];
        const float rr = gz[k][tw + 4];
        const float hh = tanh_f(xwn + rr * hun);
        const float ho = Hs[rg + 8 * k][gl + 32 * tw];
        hn[k][tw] = z * (hh - ho) + ho;   // (1-z)*h + z*h_hat
      }
    }

    __syncthreads();   // all Hs reads (Wu GEMM + ho) done before overwriting
    #pragma unroll
    for (int k = 0; k < 4; ++k) {
      #pragma unroll
      for (int tw = 0; tw < 4; ++tw)
        Hs[rg + 8 * k][gl + 32 * tw] = hn[k][tw];
    }
    // park per-row output h in the FIRST HALF of that row of d_out (no d_ws needed)
    #pragma unroll
    for (int k = 0; k < 4; ++k) {
      if (t == lens[k] - 1) {
        float* orow = out + (size_t)(r0 + rg + 8 * k) * 256;
        #pragma unroll
        for (int tw = 0; tw < 4; ++tw) orow[gl + 32 * tw] = hn[k][tw];
      }
    }
  }
}

// Pair rows (2m, 2m+1): build the swapped-concat rows, LN over 256 (shared stats), scale+shift.
__global__ __launch_bounds__(256) void out_kernel(
    const float* __restrict__ gamma, const float* __restrict__ beta,
    float* __restrict__ out)
{
  const int tid = threadIdx.x;
  const int lane = tid & 63;
  const int m = blockIdx.x * 4 + (tid >> 6);   // pair id 0..4095
  float* pa = out + (size_t)(2 * m) * 256;
  float* pb = pa + 256;
  const float oa0 = pa[lane], oa1 = pa[64 + lane];
  const float ob0 = pb[lane], ob1 = pb[64 + lane];
  float s = oa0 + oa1 + ob0 + ob1;
  float q = oa0 * oa0 + oa1 * oa1 + ob0 * ob0 + ob1 * ob1;
  #pragma unroll
  for (int msk = 1; msk < 64; msk <<= 1) { s += __shfl_xor(s, msk); q += __shfl_xor(q, msk); }
  const float mean = s * (1.f / 256.f);
  const float rstd = rsqrtf(fmaxf(q * (1.f / 256.f) - mean * mean, 0.f) + 1e-5f);
  const float g0 = gamma[lane], g1 = gamma[64 + lane], g2 = gamma[128 + lane], g3 = gamma[192 + lane];
  const float b0 = beta[lane],  b1 = beta[64 + lane],  b2 = beta[128 + lane],  b3 = beta[192 + lane];
  const float na0 = (oa0 - mean) * rstd, na1 = (oa1 - mean) * rstd;
  const float nb0 = (ob0 - mean) * rstd, nb1 = (ob1 - mean) * rstd;
  pa[lane]       = na0 * g0 + b0;
  pa[64 + lane]  = na1 * g1 + b1;
  pa[128 + lane] = nb0 * g2 + b2;
  pa[192 + lane] = nb1 * g3 + b3;
  pb[lane]       = nb0 * g0 + b0;
  pb[64 + lane]  = nb1 * g1 + b1;
  pb[128 + lane] = na0 * g2 + b2;
  pb[192 + lane] = na1 * g3 + b3;
}

extern "C" void kernel_launch(void* const* d_in, const int* in_sizes, int n_in,
                              void* d_out, int out_size, void* d_ws, size_t ws_size,
                              hipStream_t stream) {
  const int*   paths = (const int*)d_in[0];
  const int*   pmask = (const int*)d_in[1];
  const float* emb   = (const float*)d_in[2];
  const float* Wi    = (const float*)d_in[3];
  const float* bi    = (const float*)d_in[4];
  const float* Wh    = (const float*)d_in[5];
  const float* bh    = (const float*)d_in[6];
  const float* Ww    = (const float*)d_in[7];
  const float* bw    = (const float*)d_in[8];
  const float* Wu    = (const float*)d_in[9];
  const float* bu    = (const float*)d_in[10];
  const float* gamma = (const float*)d_in[11];
  const float* beta  = (const float*)d_in[12];
  float* out = (float*)d_out;
  hipLaunchKernelGGL(rec_kernel, dim3(8192 / RPB), dim3(NT), 0, stream,
                     paths, pmask, emb, Wi, bi, Wh, bh, Ww, bw, Wu, bu, out);
  hipLaunchKernelGGL(out_kernel, dim3(1024), dim3(256), 0, stream, gamma, beta, out);
}

// Round 2
// 118.500 us; speedup vs baseline: 23.2401x; 23.2401x over previous
//
#include <hip/hip_runtime.h>

#define NT 256
#define RPB 32
#define NSTEP 32

typedef float  f32x16 __attribute__((ext_vector_type(16)));
typedef short  s16x8  __attribute__((ext_vector_type(8)));

// ---- LDS layout (dynamic, 112640 B) ----
#define WH_OFF   0        // [256][128] bf16, 16B-group XOR-swizzled by (row&15)
#define WU_OFF   65536    // [128][128] bf16, same swizzle
#define H_OFF    98304    // [32][128]  bf16, same swizzle
#define RED_OFF  106496   // [4 waves][32 rows][4] f32 partial sums
#define PATH_OFF 108544   // [32 t][32 rows] int (transposed for conflict-free read)
#define LDS_BYTES 112640

__device__ __forceinline__ unsigned short bfb(float x) {  // f32 -> bf16 bits, RNE
  unsigned u = __builtin_bit_cast(unsigned, x);
  return (unsigned short)((u + 0x7FFFu + ((u >> 16) & 1u)) >> 16);
}
__device__ __forceinline__ float fast_sig(float x) {
  float e = __builtin_amdgcn_exp2f(x * -1.44269504f);
  return __builtin_amdgcn_rcpf(1.f + e);
}
__device__ __forceinline__ float fast_tanh(float x) {   // 1 - 2/(e^{2x}+1), saturates
  float e = __builtin_amdgcn_exp2f(x * 2.88539008f);
  return 1.f - 2.f * __builtin_amdgcn_rcpf(1.f + e);
}

// ---------------- Phase 1: vocab tables xi_tab[301][256], xw_tab[301][128] ----------------
__global__ __launch_bounds__(256) void tab_kernel(
    const float* __restrict__ emb,
    const float* __restrict__ Wi, const float* __restrict__ bi,
    const float* __restrict__ Ww, const float* __restrict__ bw,
    float* __restrict__ xi_tab, float* __restrict__ xw_tab)
{
  const int v = blockIdx.x;            // 0..300
  const int g = threadIdx.x;           // 0..255
  const float4* er = (const float4*)(emb + v * 128);

  float acc = bi[g];
  const float4* wr = (const float4*)(Wi + g * 128);
  #pragma unroll 8
  for (int j = 0; j < 32; ++j) {
    float4 e = er[j], w4 = wr[j];
    acc = fmaf(e.x, w4.x, acc); acc = fmaf(e.y, w4.y, acc);
    acc = fmaf(e.z, w4.z, acc); acc = fmaf(e.w, w4.w, acc);
  }
  float accw = 0.f;
  if (g < 128) {
    accw = bw[g];
    const float4* wr2 = (const float4*)(Ww + g * 128);
    #pragma unroll 8
    for (int j = 0; j < 32; ++j) {
      float4 e = er[j], w4 = wr2[j];
      accw = fmaf(e.x, w4.x, accw); accw = fmaf(e.y, w4.y, accw);
      accw = fmaf(e.z, w4.z, accw); accw = fmaf(e.w, w4.w, accw);
    }
  }
  __shared__ float rs[4][2], rw[2][2];
  float s = acc, q = acc * acc;
  #pragma unroll
  for (int m = 1; m < 64; m <<= 1) { s += __shfl_xor(s, m); q += __shfl_xor(q, m); }
  if ((threadIdx.x & 63) == 0) { rs[threadIdx.x >> 6][0] = s; rs[threadIdx.x >> 6][1] = q; }
  float sw_ = accw, qw_ = accw * accw;
  #pragma unroll
  for (int m = 1; m < 64; m <<= 1) { sw_ += __shfl_xor(sw_, m); qw_ += __shfl_xor(qw_, m); }
  if (g < 128 && (g & 63) == 0) { rw[g >> 6][0] = sw_; rw[g >> 6][1] = qw_; }
  __syncthreads();
  const float SH = rs[0][0] + rs[1][0] + rs[2][0] + rs[3][0];
  const float QH = rs[0][1] + rs[1][1] + rs[2][1] + rs[3][1];
  const float mH = SH * (1.f / 256.f);
  const float rH = rsqrtf(fmaxf(QH * (1.f / 256.f) - mH * mH, 0.f) + 1e-5f);
  xi_tab[v * 256 + g] = (acc - mH) * rH;
  if (g < 128) {
    const float SW = rw[0][0] + rw[1][0], QW = rw[0][1] + rw[1][1];
    const float mW = SW * (1.f / 128.f);
    const float rW = rsqrtf(fmaxf(QW * (1.f / 128.f) - mW * mW, 0.f) + 1e-5f);
    xw_tab[v * 128 + g] = (accw - mW) * rW;
  }
}

// ---------------- Phase 2: recurrence. 256 blocks x 256 thr; 32 rows/block ----------------
__global__ __launch_bounds__(NT, 1) void rec_kernel(
    const int* __restrict__ paths, const int* __restrict__ pmask,
    const float* __restrict__ Wh, const float* __restrict__ bh,
    const float* __restrict__ Wu, const float* __restrict__ bu,
    const float* __restrict__ xi_tab, const float* __restrict__ xw_tab,
    float* __restrict__ out)
{
  extern __shared__ char smem[];
  const int tid = threadIdx.x;
  const int w   = tid >> 6;        // wave 0..3
  const int hi  = (tid >> 5) & 1;  // lane>>5
  const int r   = tid & 31;        // h-row owned by this lane
  const int r15 = r & 15;
  const int r0  = blockIdx.x * RPB;

  // ---- stage Wh (4096 16B-chunks) and Wu (2048) as swizzled bf16 ----
  for (int c = tid; c < 4096; c += NT) {
    const int rr = c >> 4, g16 = c & 15;
    const float4* s = (const float4*)(Wh + rr * 128 + g16 * 8);
    float4 a = s[0], b = s[1];
    s16x8 vv;
    vv[0] = (short)bfb(a.x); vv[1] = (short)bfb(a.y); vv[2] = (short)bfb(a.z); vv[3] = (short)bfb(a.w);
    vv[4] = (short)bfb(b.x); vv[5] = (short)bfb(b.y); vv[6] = (short)bfb(b.z); vv[7] = (short)bfb(b.w);
    *(s16x8*)(smem + WH_OFF + rr * 256 + ((g16 ^ (rr & 15)) << 4)) = vv;
  }
  for (int c = tid; c < 2048; c += NT) {
    const int rr = c >> 4, g16 = c & 15;
    const float4* s = (const float4*)(Wu + rr * 128 + g16 * 8);
    float4 a = s[0], b = s[1];
    s16x8 vv;
    vv[0] = (short)bfb(a.x); vv[1] = (short)bfb(a.y); vv[2] = (short)bfb(a.z); vv[3] = (short)bfb(a.w);
    vv[4] = (short)bfb(b.x); vv[5] = (short)bfb(b.y); vv[6] = (short)bfb(b.z); vv[7] = (short)bfb(b.w);
    *(s16x8*)(smem + WU_OFF + rr * 256 + ((g16 ^ (rr & 15)) << 4)) = vv;
  }
  { // zero h LDS
    uint4 z{0, 0, 0, 0};
    ((uint4*)(smem + H_OFF))[tid * 2]     = z;
    ((uint4*)(smem + H_OFF))[tid * 2 + 1] = z;
  }
  { // paths transposed: pathsLT[t][row]
    int* pl = (int*)(smem + PATH_OFF);
    for (int k = tid; k < 1024; k += NT)
      pl[(k & 31) * 32 + (k >> 5)] = paths[r0 * 32 + k];
  }

  // ---- per-thread constants ----
  const int len = pmask[r0 + r];
  float bh0v[16], bh1v[16], buv[16];
  #pragma unroll
  for (int q = 0; q < 4; ++q) {
    float4 b0 = *(const float4*)(bh + 32 * w + 8 * q + 4 * hi);
    float4 b1 = *(const float4*)(bh + 128 + 32 * w + 8 * q + 4 * hi);
    float4 b2 = *(const float4*)(bu + 32 * w + 8 * q + 4 * hi);
    bh0v[4*q+0]=b0.x; bh0v[4*q+1]=b0.y; bh0v[4*q+2]=b0.z; bh0v[4*q+3]=b0.w;
    bh1v[4*q+0]=b1.x; bh1v[4*q+1]=b1.y; bh1v[4*q+2]=b1.z; bh1v[4*q+3]=b1.w;
    buv [4*q+0]=b2.x; buv [4*q+1]=b2.y; buv [4*q+2]=b2.z; buv [4*q+3]=b2.w;
  }
  int offk[8], hwoff[4];
  #pragma unroll
  for (int kk = 0; kk < 8; ++kk) offk[kk] = ((hi + 2 * kk) ^ r15) << 4;
  #pragma unroll
  for (int q = 0; q < 4; ++q) hwoff[q] = (((4 * w + q) ^ r15) << 4) + 8 * hi;

  const int whRow0 = (32 * w + r) << 8;          // byte row offsets
  const int whRow1 = (128 + 32 * w + r) << 8;
  const int wuRow  = (32 * w + r) << 8;
  const int hRow   = r << 8;
  float* red = (float*)(smem + RED_OFF);
  const int* plT = (const int*)(smem + PATH_OFF);

  float hreg[16];
  #pragma unroll
  for (int i = 0; i < 16; ++i) hreg[i] = 0.f;

  __syncthreads();

  #pragma unroll 1
  for (int t = 0; t < NSTEP; ++t) {
    // ---- gather xi/xw rows for this step (L2-resident tables) ----
    const int p = plT[t * 32 + r];
    const float* xir = xi_tab + p * 256 + 32 * w + 4 * hi;
    const float* xwr = xw_tab + p * 128 + 32 * w + 4 * hi;
    float4 xi0[4], xi1[4], xwv[4];
    #pragma unroll
    for (int q = 0; q < 4; ++q) {
      xi0[q] = *(const float4*)(xir + 8 * q);
      xi1[q] = *(const float4*)(xir + 128 + 8 * q);
      xwv[q] = *(const float4*)(xwr + 8 * q);
    }

    // ---- MFMA: D[g][r] = W·h^T for tiles {Wh w, Wh w+4, Wu w} ----
    f32x16 a0{}, a1{}, au{};
    #pragma unroll
    for (int kk = 0; kk < 8; ++kk) {
      s16x8 hb = *(const s16x8*)(smem + H_OFF  + hRow   + offk[kk]);
      s16x8 w0 = *(const s16x8*)(smem + WH_OFF + whRow0 + offk[kk]);
      s16x8 w1 = *(const s16x8*)(smem + WH_OFF + whRow1 + offk[kk]);
      s16x8 wu = *(const s16x8*)(smem + WU_OFF + wuRow  + offk[kk]);
      a0 = __builtin_amdgcn_mfma_f32_32x32x16_bf16(w0, hb, a0, 0, 0, 0);
      a1 = __builtin_amdgcn_mfma_f32_32x32x16_bf16(w1, hb, a1, 0, 0, 0);
      au = __builtin_amdgcn_mfma_f32_32x32x16_bf16(wu, hb, au, 0, 0, 0);
    }

    // ---- bias + local stats ----
    float sH = 0.f, qH = 0.f, sU = 0.f, qU = 0.f;
    #pragma unroll
    for (int i = 0; i < 16; ++i) {
      a0[i] += bh0v[i]; sH += a0[i]; qH = fmaf(a0[i], a0[i], qH);
      a1[i] += bh1v[i]; sH += a1[i]; qH = fmaf(a1[i], a1[i], qH);
      au[i] += buv[i];  sU += au[i]; qU = fmaf(au[i], au[i], qU);
    }
    sH += __shfl_xor(sH, 32); qH += __shfl_xor(qH, 32);
    sU += __shfl_xor(sU, 32); qU += __shfl_xor(qU, 32);
    if ((tid & 63) < 32) *(float4*)&red[(w * 32 + r) * 4] = float4{sH, qH, sU, qU};
    __syncthreads();   // B1: also guarantees all h frag-reads complete

    float SH = 0.f, QH = 0.f, SU = 0.f, QU = 0.f;
    #pragma unroll
    for (int ww = 0; ww < 4; ++ww) {
      float4 rr4 = *(const float4*)&red[(ww * 32 + r) * 4];
      SH += rr4.x; QH += rr4.y; SU += rr4.z; QU += rr4.w;
    }
    const float mH = SH * (1.f / 256.f);
    const float rsH = rsqrtf(fmaxf(QH * (1.f / 256.f) - mH * mH, 0.f) + 1e-5f);
    const float cH = -mH * rsH;
    const float mU = SU * (1.f / 128.f);
    const float rsU = rsqrtf(fmaxf(QU * (1.f / 128.f) - mU * mU, 0.f) + 1e-5f);
    const float cU = -mU * rsU;

    // ---- gates, candidate, state update (all thread-local) ----
    float hn[16];
    #pragma unroll
    for (int i = 0; i < 16; ++i) {
      const float xiz = ((const float*)&xi0[i >> 2])[i & 3];
      const float xirv = ((const float*)&xi1[i >> 2])[i & 3];
      const float xwvv = ((const float*)&xwv[i >> 2])[i & 3];
      const float zg = fast_sig(xiz + fmaf(a0[i], rsH, cH));
      const float rg = fast_sig(xirv + fmaf(a1[i], rsH, cH));
      const float hu = fmaf(au[i], rsU, cU);
      const float hh = fast_tanh(fmaf(rg, hu, xwvv));
      hn[i] = fmaf(zg, hh - hreg[i], hreg[i]);
    }
    if (t == len - 1) {
      float* orow = out + (size_t)(r0 + r) * 256 + 32 * w + 4 * hi;
      #pragma unroll
      for (int q = 0; q < 4; ++q)
        *(float4*)(orow + 8 * q) = float4{hn[4*q], hn[4*q+1], hn[4*q+2], hn[4*q+3]};
    }
    // ---- write h back (bf16, swizzled) ----
    #pragma unroll
    for (int q = 0; q < 4; ++q) {
      unsigned lo = (unsigned)bfb(hn[4*q+0]) | ((unsigned)bfb(hn[4*q+1]) << 16);
      unsigned hi2 = (unsigned)bfb(hn[4*q+2]) | ((unsigned)bfb(hn[4*q+3]) << 16);
      *(uint2*)(smem + H_OFF + hRow + hwoff[q]) = uint2{lo, hi2};
    }
    #pragma unroll
    for (int i = 0; i < 16; ++i) hreg[i] = hn[i];
    __syncthreads();   // B2: h visible for next step
  }
}

// ---------------- Phase 3: pair rows, final LN (unchanged from R1, verified) ----------------
__global__ __launch_bounds__(256) void out_kernel(
    const float* __restrict__ gamma, const float* __restrict__ beta,
    float* __restrict__ out)
{
  const int tid = threadIdx.x;
  const int lane = tid & 63;
  const int m = blockIdx.x * 4 + (tid >> 6);
  float* pa = out + (size_t)(2 * m) * 256;
  float* pb = pa + 256;
  const float oa0 = pa[lane], oa1 = pa[64 + lane];
  const float ob0 = pb[lane], ob1 = pb[64 + lane];
  float s = oa0 + oa1 + ob0 + ob1;
  float q = oa0 * oa0 + oa1 * oa1 + ob0 * ob0 + ob1 * ob1;
  #pragma unroll
  for (int msk = 1; msk < 64; msk <<= 1) { s += __shfl_xor(s, msk); q += __shfl_xor(q, msk); }
  const float mean = s * (1.f / 256.f);
  const float rstd = rsqrtf(fmaxf(q * (1.f / 256.f) - mean * mean, 0.f) + 1e-5f);
  const float g0 = gamma[lane], g1 = gamma[64 + lane], g2 = gamma[128 + lane], g3 = gamma[192 + lane];
  const float b0 = beta[lane],  b1 = beta[64 + lane],  b2 = beta[128 + lane],  b3 = beta[192 + lane];
  const float na0 = (oa0 - mean) * rstd, na1 = (oa1 - mean) * rstd;
  const float nb0 = (ob0 - mean) * rstd, nb1 = (ob1 - mean) * rstd;
  pa[lane]       = na0 * g0 + b0;
  pa[64 + lane]  = na1 * g1 + b1;
  pa[128 + lane] = nb0 * g2 + b2;
  pa[192 + lane] = nb1 * g3 + b3;
  pb[lane]       = nb0 * g0 + b0;
  pb[64 + lane]  = nb1 * g1 + b1;
  pb[128 + lane] = na0 * g2 + b2;
  pb[192 + lane] = na1 * g3 + b3;
}

extern "C" void kernel_launch(void* const* d_in, const int* in_sizes, int n_in,
                              void* d_out, int out_size, void* d_ws, size_t ws_size,
                              hipStream_t stream) {
  const int*   paths = (const int*)d_in[0];
  const int*   pmask = (const int*)d_in[1];
  const float* emb   = (const float*)d_in[2];
  const float* Wi    = (const float*)d_in[3];
  const float* bi    = (const float*)d_in[4];
  const float* Wh    = (const float*)d_in[5];
  const float* bh    = (const float*)d_in[6];
  const float* Ww    = (const float*)d_in[7];
  const float* bw    = (const float*)d_in[8];
  const float* Wu    = (const float*)d_in[9];
  const float* bu    = (const float*)d_in[10];
  const float* gamma = (const float*)d_in[11];
  const float* beta  = (const float*)d_in[12];
  float* out = (float*)d_out;

  float* xi_tab = (float*)d_ws;            // [301][256]
  float* xw_tab = xi_tab + 301 * 256;      // [301][128]

  static bool attr_done = false;
  if (!attr_done) {
    hipFuncSetAttribute((const void*)rec_kernel,
                        hipFuncAttributeMaxDynamicSharedMemorySize, LDS_BYTES);
    attr_done = true;
  }

  hipLaunchKernelGGL(tab_kernel, dim3(301), dim3(256), 0, stream,
                     emb, Wi, bi, Ww, bw, xi_tab, xw_tab);
  hipLaunchKernelGGL(rec_kernel, dim3(8192 / RPB), dim3(NT), LDS_BYTES, stream,
                     paths, pmask, Wh, bh, Wu, bu, xi_tab, xw_tab, out);
  hipLaunchKernelGGL(out_kernel, dim3(1024), dim3(256), 0, stream, gamma, beta, out);
}

// Round 3
// 112.973 us; speedup vs baseline: 24.3769x; 1.0489x over previous
//
#include <hip/hip_runtime.h>

#define NSTEP 32

typedef float  f32x4 __attribute__((ext_vector_type(4)));
typedef short  s16x8 __attribute__((ext_vector_type(8)));

__device__ __forceinline__ unsigned short bfb(float x) {  // f32 -> bf16 bits, RNE
  unsigned u = __builtin_bit_cast(unsigned, x);
  return (unsigned short)((u + 0x7FFFu + ((u >> 16) & 1u)) >> 16);
}
__device__ __forceinline__ float fast_sig(float x) {
  float e = __builtin_amdgcn_exp2f(x * -1.44269504f);
  return __builtin_amdgcn_rcpf(1.f + e);
}
__device__ __forceinline__ float fast_tanh(float x) {
  float e = __builtin_amdgcn_exp2f(x * 2.88539008f);
  return 1.f - 2.f * __builtin_amdgcn_rcpf(1.f + e);
}

// ---------- Phase 1: vocab tables (blocks 0..300) + weight A-fragments (blocks 301..308) ----
// frags layout: [tile(3)][kk(4)][tid(512)] s16x8, tid = w*64+lane.
// A-frag (mfma_f32_16x16x32_bf16): lane l holds A row = l&15, k = (l>>4)*8 + j  (j=0..7)
__global__ __launch_bounds__(256) void tab_kernel(
    const float* __restrict__ emb,
    const float* __restrict__ Wi, const float* __restrict__ bi,
    const float* __restrict__ Ww, const float* __restrict__ bw,
    const float* __restrict__ Wh, const float* __restrict__ Wu,
    float* __restrict__ xi_tab, float* __restrict__ xw_tab,
    s16x8* __restrict__ frags)
{
  if (blockIdx.x >= 301) {
    const int w = blockIdx.x - 301;      // wave-role 0..7
    const int lane = threadIdx.x;
    if (lane >= 64) return;
    const int a = lane & 15, s = lane >> 4;
    const float* rowp[3];
    rowp[0] = Wh + (16 * w + a) * 128;          // z tile
    rowp[1] = Wh + (128 + 16 * w + a) * 128;    // r tile
    rowp[2] = Wu + (16 * w + a) * 128;          // hu tile
    #pragma unroll
    for (int tile = 0; tile < 3; ++tile) {
      #pragma unroll
      for (int kk = 0; kk < 4; ++kk) {
        const float* src = rowp[tile] + 32 * kk + 8 * s;
        const float4 A = *(const float4*)src;
        const float4 B = *(const float4*)(src + 4);
        s16x8 v;
        v[0] = (short)bfb(A.x); v[1] = (short)bfb(A.y);
        v[2] = (short)bfb(A.z); v[3] = (short)bfb(A.w);
        v[4] = (short)bfb(B.x); v[5] = (short)bfb(B.y);
        v[6] = (short)bfb(B.z); v[7] = (short)bfb(B.w);
        frags[(tile * 4 + kk) * 512 + w * 64 + lane] = v;
      }
    }
    return;
  }

  const int v = blockIdx.x;            // 0..300
  const int g = threadIdx.x;           // 0..255
  const float4* er = (const float4*)(emb + v * 128);

  float acc = bi[g];
  const float4* wr = (const float4*)(Wi + g * 128);
  #pragma unroll 8
  for (int j = 0; j < 32; ++j) {
    float4 e = er[j], w4 = wr[j];
    acc = fmaf(e.x, w4.x, acc); acc = fmaf(e.y, w4.y, acc);
    acc = fmaf(e.z, w4.z, acc); acc = fmaf(e.w, w4.w, acc);
  }
  float accw = 0.f;
  if (g < 128) {
    accw = bw[g];
    const float4* wr2 = (const float4*)(Ww + g * 128);
    #pragma unroll 8
    for (int j = 0; j < 32; ++j) {
      float4 e = er[j], w4 = wr2[j];
      accw = fmaf(e.x, w4.x, accw); accw = fmaf(e.y, w4.y, accw);
      accw = fmaf(e.z, w4.z, accw); accw = fmaf(e.w, w4.w, accw);
    }
  }
  __shared__ float rs[4][2], rw[2][2];
  float s = acc, q = acc * acc;
  #pragma unroll
  for (int m = 1; m < 64; m <<= 1) { s += __shfl_xor(s, m); q += __shfl_xor(q, m); }
  if ((threadIdx.x & 63) == 0) { rs[threadIdx.x >> 6][0] = s; rs[threadIdx.x >> 6][1] = q; }
  float sw_ = accw, qw_ = accw * accw;
  #pragma unroll
  for (int m = 1; m < 64; m <<= 1) { sw_ += __shfl_xor(sw_, m); qw_ += __shfl_xor(qw_, m); }
  if (g < 128 && (g & 63) == 0) { rw[g >> 6][0] = sw_; rw[g >> 6][1] = qw_; }
  __syncthreads();
  const float SH = rs[0][0] + rs[1][0] + rs[2][0] + rs[3][0];
  const float QH = rs[0][1] + rs[1][1] + rs[2][1] + rs[3][1];
  const float mH = SH * (1.f / 256.f);
  const float rH = rsqrtf(fmaxf(QH * (1.f / 256.f) - mH * mH, 0.f) + 1e-5f);
  xi_tab[v * 256 + g] = (acc - mH) * rH;
  if (g < 128) {
    const float SW = rw[0][0] + rw[1][0], QW = rw[0][1] + rw[1][1];
    const float mW = SW * (1.f / 128.f);
    const float rW = rsqrtf(fmaxf(QW * (1.f / 128.f) - mW * mW, 0.f) + 1e-5f);
    xw_tab[v * 128 + g] = (accw - mW) * rW;
  }
}

// ---------- Phase 2: recurrence. 512 blocks x 512 thr (8 waves), 16 rows/block ----------
// Wave w owns triple {Wh z-tile w, Wh r-tile w, Wu tile w}: g in [16w,16w+16).
// Thread (w, s=lane>>4, r=lane&15): D elems g = 16w+4s+i, h-row r.
__global__ __launch_bounds__(512, 4) void rec_kernel(
    const int* __restrict__ paths, const int* __restrict__ pmask,
    const float* __restrict__ bh, const float* __restrict__ bu,
    const float* __restrict__ xi_tab, const float* __restrict__ xw_tab,
    const s16x8* __restrict__ frags,
    float* __restrict__ out)
{
  __shared__ unsigned char hbuf[4096];   // h [16][128] bf16, 16B-chunk XOR(r) swizzled
  __shared__ float red[8 * 16 * 4];      // [wave][row]{sH,qH,sU,qU}
  __shared__ int plT[512];               // paths transposed [t][row]

  const int tid  = threadIdx.x;
  const int w    = tid >> 6;
  const int lane = tid & 63;
  const int s    = lane >> 4;
  const int r    = lane & 15;
  const int r0   = blockIdx.x * 16;
  const int gbase = 16 * w + 4 * s;

  // weight A-fragments (persistent, 48 VGPR)
  s16x8 wz[4], wr[4], wu4[4];
  #pragma unroll
  for (int kk = 0; kk < 4; ++kk) {
    wz[kk]  = frags[kk * 512 + tid];
    wr[kk]  = frags[(4 + kk) * 512 + tid];
    wu4[kk] = frags[(8 + kk) * 512 + tid];
  }

  plT[tid] = paths[(r0 + (tid & 15)) * 32 + (tid >> 4)];
  ((uint2*)hbuf)[tid] = uint2{0u, 0u};

  const int len = pmask[r0 + r];
  const f32x4 bz  = *(const f32x4*)(bh + gbase);
  const f32x4 brr = *(const f32x4*)(bh + 128 + gbase);
  const f32x4 buu = *(const f32x4*)(bu + gbase);

  // B-frag read addrs: lane reads h[r][32kk + 8s .. +7]; chunk = 4kk+s, XOR r
  int hoff[4];
  #pragma unroll
  for (int kk = 0; kk < 4; ++kk)
    hoff[kk] = r * 256 + (((4 * kk + s) ^ r) << 4);
  // write addr: cols gbase..gbase+3 -> bytes 32w+8s, chunk 2w+(s>>1), sub-off 8*(s&1)
  const int hwadr = r * 256 + (((2 * w + (s >> 1)) ^ r) << 4) + (s & 1) * 8;

  float hreg[4] = {0.f, 0.f, 0.f, 0.f};
  float* orow = out + (size_t)(r0 + r) * 256 + gbase;

  __syncthreads();

  #pragma unroll 1
  for (int t = 0; t < NSTEP; ++t) {
    const int p = plT[t * 16 + r];
    const f32x4 xiz = *(const f32x4*)(xi_tab + p * 256 + gbase);
    const f32x4 xir = *(const f32x4*)(xi_tab + p * 256 + 128 + gbase);
    const f32x4 xwv = *(const f32x4*)(xw_tab + p * 128 + gbase);

    f32x4 az{}, ar{}, au{};
    #pragma unroll
    for (int kk = 0; kk < 4; ++kk) {
      const s16x8 hb = *(const s16x8*)(hbuf + hoff[kk]);
      az = __builtin_amdgcn_mfma_f32_16x16x32_bf16(wz[kk],  hb, az, 0, 0, 0);
      ar = __builtin_amdgcn_mfma_f32_16x16x32_bf16(wr[kk],  hb, ar, 0, 0, 0);
      au = __builtin_amdgcn_mfma_f32_16x16x32_bf16(wu4[kk], hb, au, 0, 0, 0);
    }

    // bias + per-thread partial LN stats (H over z&r parts, U over hu part)
    float sH = 0.f, qH = 0.f, sU = 0.f, qU = 0.f;
    #pragma unroll
    for (int i = 0; i < 4; ++i) {
      az[i] += bz[i];  sH += az[i]; qH = fmaf(az[i], az[i], qH);
      ar[i] += brr[i]; sH += ar[i]; qH = fmaf(ar[i], ar[i], qH);
      au[i] += buu[i]; sU += au[i]; qU = fmaf(au[i], au[i], qU);
    }
    // reduce across the 4 lanes sharing row r (xor 16, 32)
    sH += __shfl_xor(sH, 16); qH += __shfl_xor(qH, 16);
    sU += __shfl_xor(sU, 16); qU += __shfl_xor(qU, 16);
    sH += __shfl_xor(sH, 32); qH += __shfl_xor(qH, 32);
    sU += __shfl_xor(sU, 32); qU += __shfl_xor(qU, 32);
    if (lane < 16) *(f32x4*)&red[(w * 16 + r) * 4] = f32x4{sH, qH, sU, qU};
    __syncthreads();   // B1: stats visible; all h reads complete

    float SH = 0.f, QH = 0.f, SU = 0.f, QU = 0.f;
    #pragma unroll
    for (int ww = 0; ww < 8; ++ww) {
      const f32x4 rr4 = *(const f32x4*)&red[(ww * 16 + r) * 4];
      SH += rr4[0]; QH += rr4[1]; SU += rr4[2]; QU += rr4[3];
    }
    const float mH = SH * (1.f / 256.f);
    const float rsH = rsqrtf(fmaxf(QH * (1.f / 256.f) - mH * mH, 0.f) + 1e-5f);
    const float cH = -mH * rsH;
    const float mU = SU * (1.f / 128.f);
    const float rsU = rsqrtf(fmaxf(QU * (1.f / 128.f) - mU * mU, 0.f) + 1e-5f);
    const float cU = -mU * rsU;

    float hn[4];
    #pragma unroll
    for (int i = 0; i < 4; ++i) {
      const float zg = fast_sig(xiz[i] + fmaf(az[i], rsH, cH));
      const float rg = fast_sig(xir[i] + fmaf(ar[i], rsH, cH));
      const float hu = fmaf(au[i], rsU, cU);
      const float hh = fast_tanh(fmaf(rg, hu, xwv[i]));
      hn[i] = fmaf(zg, hh - hreg[i], hreg[i]);
    }
    if (t == len - 1)
      *(float4*)orow = float4{hn[0], hn[1], hn[2], hn[3]};

    const unsigned lo  = (unsigned)bfb(hn[0]) | ((unsigned)bfb(hn[1]) << 16);
    const unsigned hi2 = (unsigned)bfb(hn[2]) | ((unsigned)bfb(hn[3]) << 16);
    *(uint2*)(hbuf + hwadr) = uint2{lo, hi2};
    #pragma unroll
    for (int i = 0; i < 4; ++i) hreg[i] = hn[i];
    __syncthreads();   // B2: new h visible for next step
  }
}

// ---------- Phase 3: pair rows, final LN (verified in R1/R2) ----------
__global__ __launch_bounds__(256) void out_kernel(
    const float* __restrict__ gamma, const float* __restrict__ beta,
    float* __restrict__ out)
{
  const int tid = threadIdx.x;
  const int lane = tid & 63;
  const int m = blockIdx.x * 4 + (tid >> 6);
  float* pa = out + (size_t)(2 * m) * 256;
  float* pb = pa + 256;
  const float oa0 = pa[lane], oa1 = pa[64 + lane];
  const float ob0 = pb[lane], ob1 = pb[64 + lane];
  float s = oa0 + oa1 + ob0 + ob1;
  float q = oa0 * oa0 + oa1 * oa1 + ob0 * ob0 + ob1 * ob1;
  #pragma unroll
  for (int msk = 1; msk < 64; msk <<= 1) { s += __shfl_xor(s, msk); q += __shfl_xor(q, msk); }
  const float mean = s * (1.f / 256.f);
  const float rstd = rsqrtf(fmaxf(q * (1.f / 256.f) - mean * mean, 0.f) + 1e-5f);
  const float g0 = gamma[lane], g1 = gamma[64 + lane], g2 = gamma[128 + lane], g3 = gamma[192 + lane];
  const float b0 = beta[lane],  b1 = beta[64 + lane],  b2 = beta[128 + lane],  b3 = beta[192 + lane];
  const float na0 = (oa0 - mean) * rstd, na1 = (oa1 - mean) * rstd;
  const float nb0 = (ob0 - mean) * rstd, nb1 = (ob1 - mean) * rstd;
  pa[lane]       = na0 * g0 + b0;
  pa[64 + lane]  = na1 * g1 + b1;
  pa[128 + lane] = nb0 * g2 + b2;
  pa[192 + lane] = nb1 * g3 + b3;
  pb[lane]       = nb0 * g0 + b0;
  pb[64 + lane]  = nb1 * g1 + b1;
  pb[128 + lane] = na0 * g2 + b2;
  pb[192 + lane] = na1 * g3 + b3;
}

extern "C" void kernel_launch(void* const* d_in, const int* in_sizes, int n_in,
                              void* d_out, int out_size, void* d_ws, size_t ws_size,
                              hipStream_t stream) {
  const int*   paths = (const int*)d_in[0];
  const int*   pmask = (const int*)d_in[1];
  const float* emb   = (const float*)d_in[2];
  const float* Wi    = (const float*)d_in[3];
  const float* bi    = (const float*)d_in[4];
  const float* Wh    = (const float*)d_in[5];
  const float* bh    = (const float*)d_in[6];
  const float* Ww    = (const float*)d_in[7];
  const float* bw    = (const float*)d_in[8];
  const float* Wu    = (const float*)d_in[9];
  const float* bu    = (const float*)d_in[10];
  const float* gamma = (const float*)d_in[11];
  const float* beta  = (const float*)d_in[12];
  float* out = (float*)d_out;

  float* xi_tab = (float*)d_ws;                          // [301][256] f32
  float* xw_tab = xi_tab + 301 * 256;                    // [301][128] f32
  s16x8* frags  = (s16x8*)((char*)d_ws + 462336);        // [3][4][512] s16x8 = 96 KB

  hipLaunchKernelGGL(tab_kernel, dim3(309), dim3(256), 0, stream,
                     emb, Wi, bi, Ww, bw, Wh, Wu, xi_tab, xw_tab, frags);
  hipLaunchKernelGGL(rec_kernel, dim3(512), dim3(512), 0, stream,
                     paths, pmask, bh, bu, xi_tab, xw_tab, frags, out);
  hipLaunchKernelGGL(out_kernel, dim3(1024), dim3(256), 0, stream, gamma, beta, out);
}